// Round 2
// baseline (25696.646 us; speedup 1.0000x reference)
//
#include <hip/hip_runtime.h>
#include <cmath>

#define B_ 64
#define S_ 1024
#define I_ 512
#define H_ 1024
#define O_ 512
#define HB (H_ * B_)   // 65536
#define NBLK 256
#define NTHR 512

// ---------------------------------------------------------------------------
// Input projection: xp[s][h][b] = sum_i x[b][s][i] * Wih[h][i] + bih[h] + bhh[h]
// ---------------------------------------------------------------------------
__global__ __launch_bounds__(256) void k_inproj(const float* __restrict__ x,
                                                const float* __restrict__ Wih,
                                                const float* __restrict__ bih,
                                                const float* __restrict__ bhh,
                                                float* __restrict__ xp) {
  __shared__ float As[64][36];
  __shared__ float Bs[32][72];
  const int s  = blockIdx.y;
  const int h0 = blockIdx.x * 64;
  const int t  = threadIdx.x;
  const int tx = t & 15, ty = t >> 4;
  float acc[4][4] = {};
  for (int k0 = 0; k0 < I_; k0 += 32) {
    #pragma unroll
    for (int L = 0; L < 2; L++) {
      int f = L * 256 + t;
      int row = f >> 3, c4 = (f & 7) * 4;
      float4 v = *(const float4*)&Wih[(size_t)(h0 + row) * I_ + k0 + c4];
      *(float4*)&As[row][c4] = v;
    }
    #pragma unroll
    for (int L = 0; L < 2; L++) {
      int f = L * 256 + t;
      int row = f >> 3, c4 = (f & 7) * 4;   // row = b
      float4 v = *(const float4*)&x[(size_t)row * (S_ * I_) + (size_t)s * I_ + k0 + c4];
      Bs[c4 + 0][row] = v.x;
      Bs[c4 + 1][row] = v.y;
      Bs[c4 + 2][row] = v.z;
      Bs[c4 + 3][row] = v.w;
    }
    __syncthreads();
    #pragma unroll
    for (int k = 0; k < 32; k += 4) {
      float4 a[4], b[4];
      #pragma unroll
      for (int r = 0; r < 4; r++) a[r] = *(const float4*)&As[ty * 4 + r][k];
      #pragma unroll
      for (int kk = 0; kk < 4; kk++) b[kk] = *(const float4*)&Bs[k + kk][tx * 4];
      #pragma unroll
      for (int kk = 0; kk < 4; kk++)
        #pragma unroll
        for (int r = 0; r < 4; r++)
          #pragma unroll
          for (int c = 0; c < 4; c++)
            acc[r][c] += ((const float*)&a[r])[kk] * ((const float*)&b[kk])[c];
    }
    __syncthreads();
  }
  #pragma unroll
  for (int r = 0; r < 4; r++) {
    int h = h0 + ty * 4 + r;
    float bias = bih[h] + bhh[h];
    float4 o;
    o.x = acc[r][0] + bias;
    o.y = acc[r][1] + bias;
    o.z = acc[r][2] + bias;
    o.w = acc[r][3] + bias;
    *(float4*)&xp[(size_t)s * HB + (size_t)h * 64 + tx * 4] = o;
  }
}

// ---------------------------------------------------------------------------
// Persistent cooperative scan. 256 blocks x 512 threads (1 block/CU).
// Block owns j0..j0+3 output rows. W_hh slice staged k-major in LDS once.
// Per step: 8 waves split K (128 each), 4 FMAs/k/thread, LDS reduce, tanh,
// then a monotonic-counter grid barrier with device-scope fences (G16).
// ---------------------------------------------------------------------------
__device__ __forceinline__ void gridbar(unsigned* cnt, unsigned target) {
  __syncthreads();
  if (threadIdx.x == 0) {
    __threadfence();   // release: drain + L2 writeback so other XCDs see h
    __hip_atomic_fetch_add(cnt, 1u, __ATOMIC_ACQ_REL, __HIP_MEMORY_SCOPE_AGENT);
    while (__hip_atomic_load(cnt, __ATOMIC_ACQUIRE, __HIP_MEMORY_SCOPE_AGENT) < target)
      __builtin_amdgcn_s_sleep(2);
    __threadfence();   // acquire: invalidate so we read fresh h next step
  }
  __syncthreads();
}

__global__ __launch_bounds__(NTHR) void k_scan(const float* __restrict__ hT0,
                                               const float* __restrict__ Whh,
                                               float* __restrict__ xp,
                                               unsigned* __restrict__ bar) {
  __shared__ float Ws[1024][4];    // Ws[k][jl] = Whh[j0+jl][k], 16 KB
  __shared__ float red[8][4][64];  // 8 KB
  const int t  = threadIdx.x;
  const int b  = t & 63;
  const int w  = __builtin_amdgcn_readfirstlane(t >> 6);  // wave 0..7 (SGPR)
  const int j0 = blockIdx.x * 4;

  // One-time W stage (coalesced global read, scattered LDS write — amortized)
  for (int idx = t; idx < 4096; idx += NTHR) {
    int jl = idx >> 10, k = idx & 1023;
    Ws[k][jl] = Whh[(size_t)(j0 + jl) * H_ + k];
  }
  __syncthreads();

  const float* hprev = hT0;
  for (int s = 0; s < S_; s++) {
    float* hcur = xp + (size_t)s * HB;
    const float* hp  = hprev + (size_t)(w * 128) * 64 + b;
    const float* wsp = &Ws[w * 128][0];
    float a0 = 0.f, a1 = 0.f, a2 = 0.f, a3 = 0.f;
    #pragma unroll 16
    for (int k = 0; k < 128; k++) {
      float  hv = hp[k * 64];                       // coalesced 256B/wave
      float4 wv = *(const float4*)(wsp + k * 4);    // lane-uniform broadcast
      a0 += hv * wv.x; a1 += hv * wv.y; a2 += hv * wv.z; a3 += hv * wv.w;
    }
    red[w][0][b] = a0; red[w][1][b] = a1; red[w][2][b] = a2; red[w][3][b] = a3;
    __syncthreads();
    if (t < 256) {
      const int j = t >> 6, bb = t & 63;
      float sum = 0.f;
      #pragma unroll
      for (int ww = 0; ww < 8; ww++) sum += red[ww][j][bb];
      const size_t oi = (size_t)(j0 + j) * 64 + bb;
      hcur[oi] = tanhf(hcur[oi] + sum);
    }
    gridbar(bar, (unsigned)((s + 1) * NBLK));
    hprev = hcur;
  }
}

// ---------------------------------------------------------------------------
// Output projection: out[b][s][o] = sum_h hs[s][h][b] * Who[o][h] + bho[o]
// ---------------------------------------------------------------------------
__global__ __launch_bounds__(256) void k_outproj(const float* __restrict__ hs,
                                                 const float* __restrict__ Who,
                                                 const float* __restrict__ bho,
                                                 float* __restrict__ out) {
  __shared__ float As[32][72];
  __shared__ float Bs[32][72];
  const int s  = blockIdx.y;
  const int o0 = blockIdx.x * 64;
  const int t  = threadIdx.x;
  const int tx = t & 15, ty = t >> 4;
  const float* __restrict__ hsS = hs + (size_t)s * HB;
  float acc[4][4] = {};
  for (int k0 = 0; k0 < H_; k0 += 32) {
    #pragma unroll
    for (int L = 0; L < 2; L++) {
      int f = L * 256 + t;
      int kk = f >> 4, b4 = (f & 15) * 4;
      *(float4*)&As[kk][b4] = *(const float4*)&hsS[(size_t)(k0 + kk) * 64 + b4];
    }
    #pragma unroll
    for (int L = 0; L < 2; L++) {
      int f = L * 256 + t;
      int row = f >> 3, c4 = (f & 7) * 4;   // row = o
      float4 v = *(const float4*)&Who[(size_t)(o0 + row) * H_ + k0 + c4];
      Bs[c4 + 0][row] = v.x;
      Bs[c4 + 1][row] = v.y;
      Bs[c4 + 2][row] = v.z;
      Bs[c4 + 3][row] = v.w;
    }
    __syncthreads();
    #pragma unroll
    for (int k = 0; k < 32; k += 4) {
      float4 a4[4], b4[4];
      #pragma unroll
      for (int kk = 0; kk < 4; kk++) a4[kk] = *(const float4*)&As[k + kk][ty * 4];
      #pragma unroll
      for (int kk = 0; kk < 4; kk++) b4[kk] = *(const float4*)&Bs[k + kk][tx * 4];
      #pragma unroll
      for (int kk = 0; kk < 4; kk++)
        #pragma unroll
        for (int r = 0; r < 4; r++)
          #pragma unroll
          for (int c = 0; c < 4; c++)
            acc[r][c] += ((const float*)&a4[kk])[r] * ((const float*)&b4[kk])[c];
    }
    __syncthreads();
  }
  #pragma unroll
  for (int r = 0; r < 4; r++) {
    int b = ty * 4 + r;
    float4 o4;
    o4.x = acc[r][0] + bho[o0 + tx * 4 + 0];
    o4.y = acc[r][1] + bho[o0 + tx * 4 + 1];
    o4.z = acc[r][2] + bho[o0 + tx * 4 + 2];
    o4.w = acc[r][3] + bho[o0 + tx * 4 + 3];
    *(float4*)&out[(size_t)b * (S_ * O_) + (size_t)s * O_ + o0 + tx * 4] = o4;
  }
}

// (B,H) -> (H,B)
__global__ void k_transpose_bh_to_hb(const float* __restrict__ src, float* __restrict__ dst) {
  int idx = blockIdx.x * 256 + threadIdx.x;  // 65536 total
  int h = idx >> 6, b = idx & 63;
  dst[h * 64 + b] = src[b * H_ + h];
}

// last hidden: (H,B) slice -> out (B,H)
__global__ void k_lasth(const float* __restrict__ hlast, float* __restrict__ out) {
  int idx = blockIdx.x * 256 + threadIdx.x;  // 65536 total
  int b = idx >> 10, h = idx & 1023;
  out[idx] = hlast[h * 64 + b];
}

extern "C" void kernel_launch(void* const* d_in, const int* in_sizes, int n_in,
                              void* d_out, int out_size, void* d_ws, size_t ws_size,
                              hipStream_t stream) {
  const float* x    = (const float*)d_in[0];
  const float* h0   = (const float*)d_in[1];
  const float* Wih  = (const float*)d_in[2];
  const float* bih  = (const float*)d_in[3];
  const float* Whh  = (const float*)d_in[4];
  const float* bhh  = (const float*)d_in[5];
  const float* Who  = (const float*)d_in[6];
  const float* bho  = (const float*)d_in[7];
  float* out = (float*)d_out;

  // ws layout: xp/hs (S,H,B) fp32 = 268.4 MB | hT0 (H,B) = 256 KB | barrier u32
  float*    xp  = (float*)d_ws;
  float*    hT0 = xp + (size_t)S_ * HB;
  unsigned* bar = (unsigned*)(hT0 + HB);

  hipMemsetAsync(bar, 0, sizeof(unsigned), stream);
  k_transpose_bh_to_hb<<<256, 256, 0, stream>>>(h0, hT0);
  k_inproj<<<dim3(16, S_), 256, 0, stream>>>(x, Wih, bih, bhh, xp);

  void* args[] = {(void*)&hT0, (void*)&Whh, (void*)&xp, (void*)&bar};
  hipLaunchCooperativeKernel((const void*)k_scan, dim3(NBLK), dim3(NTHR),
                             args, 0, stream);

  k_outproj<<<dim3(8, S_), 256, 0, stream>>>(xp, Who, bho, out);
  k_lasth<<<256, 256, 0, stream>>>(xp + (size_t)(S_ - 1) * HB, out + (size_t)B_ * S_ * O_);
}

// Round 3
// 16371.121 us; speedup vs baseline: 1.5696x; 1.5696x over previous
//
#include <hip/hip_runtime.h>
#include <cmath>

#define B_ 64
#define S_ 1024
#define I_ 512
#define H_ 1024
#define O_ 512
#define HB (H_ * B_)   // 65536
#define NBLK 256
#define NTHR 512
#define NSLOT 16
#define SLOT_STRIDE 32   // 128 B between counters

// ---------------------------------------------------------------------------
// Input projection: xp[s][h][b] = sum_i x[b][s][i] * Wih[h][i] + bih[h] + bhh[h]
// ---------------------------------------------------------------------------
__global__ __launch_bounds__(256) void k_inproj(const float* __restrict__ x,
                                                const float* __restrict__ Wih,
                                                const float* __restrict__ bih,
                                                const float* __restrict__ bhh,
                                                float* __restrict__ xp) {
  __shared__ float As[64][36];
  __shared__ float Bs[32][72];
  const int s  = blockIdx.y;
  const int h0 = blockIdx.x * 64;
  const int t  = threadIdx.x;
  const int tx = t & 15, ty = t >> 4;
  float acc[4][4] = {};
  for (int k0 = 0; k0 < I_; k0 += 32) {
    #pragma unroll
    for (int L = 0; L < 2; L++) {
      int f = L * 256 + t;
      int row = f >> 3, c4 = (f & 7) * 4;
      float4 v = *(const float4*)&Wih[(size_t)(h0 + row) * I_ + k0 + c4];
      *(float4*)&As[row][c4] = v;
    }
    #pragma unroll
    for (int L = 0; L < 2; L++) {
      int f = L * 256 + t;
      int row = f >> 3, c4 = (f & 7) * 4;   // row = b
      float4 v = *(const float4*)&x[(size_t)row * (S_ * I_) + (size_t)s * I_ + k0 + c4];
      Bs[c4 + 0][row] = v.x;
      Bs[c4 + 1][row] = v.y;
      Bs[c4 + 2][row] = v.z;
      Bs[c4 + 3][row] = v.w;
    }
    __syncthreads();
    #pragma unroll
    for (int k = 0; k < 32; k += 4) {
      float4 a[4], b[4];
      #pragma unroll
      for (int r = 0; r < 4; r++) a[r] = *(const float4*)&As[ty * 4 + r][k];
      #pragma unroll
      for (int kk = 0; kk < 4; kk++) b[kk] = *(const float4*)&Bs[k + kk][tx * 4];
      #pragma unroll
      for (int kk = 0; kk < 4; kk++)
        #pragma unroll
        for (int r = 0; r < 4; r++)
          #pragma unroll
          for (int c = 0; c < 4; c++)
            acc[r][c] += ((const float*)&a[r])[kk] * ((const float*)&b[kk])[c];
    }
    __syncthreads();
  }
  #pragma unroll
  for (int r = 0; r < 4; r++) {
    int h = h0 + ty * 4 + r;
    float bias = bih[h] + bhh[h];
    float4 o;
    o.x = acc[r][0] + bias;
    o.y = acc[r][1] + bias;
    o.z = acc[r][2] + bias;
    o.w = acc[r][3] + bias;
    *(float4*)&xp[(size_t)s * HB + (size_t)h * 64 + tx * 4] = o;
  }
}

// ---------------------------------------------------------------------------
// Persistent cooperative scan, 256 blocks x 512 threads (1 block/CU).
// Block owns 4 output rows. W_hh rows are wave-uniform const-restrict reads
// -> s_load through scalar K$ (not touched by buffer_inv, stays hot).
// h_{t-1} read via normal cached loads (L2); h_t written via relaxed agent
// atomic stores (sc1 write-through -> no dirty L2, no wbl2 needed).
// Barrier: relaxed fetch_add on 16 spread counters + relaxed polling
// (NO acquire in the loop!), then exactly one agent acquire fence
// (buffer_inv) per block per step.
// ---------------------------------------------------------------------------
__global__ __launch_bounds__(NTHR) void k_scan(const float* __restrict__ hT0,
                                               const float* __restrict__ Whh,
                                               float* __restrict__ xp,
                                               unsigned* __restrict__ bar) {
  __shared__ float red[8][4][64];  // 8 KB
  const int t = threadIdx.x;
  const int b = t & 63;
  const int w = t >> 6;            // wave 0..7, k-slice of 128
  const int j0 = blockIdx.x * 4;

  const float* __restrict__ wr0 = Whh + (size_t)(j0 + 0) * H_ + w * 128;
  const float* __restrict__ wr1 = Whh + (size_t)(j0 + 1) * H_ + w * 128;
  const float* __restrict__ wr2 = Whh + (size_t)(j0 + 2) * H_ + w * 128;
  const float* __restrict__ wr3 = Whh + (size_t)(j0 + 3) * H_ + w * 128;

  const float* hprev = hT0;
  for (int s = 0; s < S_; s++) {
    float* hcur = xp + (size_t)s * HB;
    const float* hp = hprev + (size_t)(w * 128) * 64 + b;

    float a0 = 0.f, a1 = 0.f, a2 = 0.f, a3 = 0.f;
    #pragma unroll 8
    for (int k = 0; k < 128; k++) {
      float hv = hp[(size_t)k * 64];        // cached, coalesced 256B/wave
      a0 = fmaf(wr0[k], hv, a0);            // wr*[k] wave-uniform -> s_load
      a1 = fmaf(wr1[k], hv, a1);
      a2 = fmaf(wr2[k], hv, a2);
      a3 = fmaf(wr3[k], hv, a3);
    }
    red[w][0][b] = a0; red[w][1][b] = a1; red[w][2][b] = a2; red[w][3][b] = a3;
    __syncthreads();
    if (t < 256) {
      const int j = t >> 6, bb = t & 63;
      float sum = 0.f;
      #pragma unroll
      for (int ww = 0; ww < 8; ww++) sum += red[ww][j][bb];
      const size_t oi = (size_t)(j0 + j) * 64 + bb;
      float v = tanhf(hcur[oi] + sum);
      // write-through to agent coherence point (IF$): no dirty L2 line
      __hip_atomic_store(&hcur[oi], v, __ATOMIC_RELAXED, __HIP_MEMORY_SCOPE_AGENT);
    }
    // ---- grid barrier (steady state: zero cache-maintenance ops) ----
    __syncthreads();   // codegen drains vmcnt per wave -> all sc1 stores done
    if (t == 0) {
      __hip_atomic_fetch_add(&bar[(blockIdx.x & (NSLOT - 1)) * SLOT_STRIDE], 1u,
                             __ATOMIC_RELAXED, __HIP_MEMORY_SCOPE_AGENT);
      const unsigned need = (unsigned)(s + 1) * NBLK;
      for (;;) {
        unsigned tot = 0;
        #pragma unroll
        for (int i = 0; i < NSLOT; i++)
          tot += __hip_atomic_load(&bar[i * SLOT_STRIDE],
                                   __ATOMIC_RELAXED, __HIP_MEMORY_SCOPE_AGENT);
        if (tot >= need) break;
        __builtin_amdgcn_s_sleep(1);
      }
    }
    __syncthreads();
    if (t < 64) {
      // exactly one buffer_inv per block per step: drop stale clean L2/L1
      // lines so the next step's cached h reads refetch from IF$
      __builtin_amdgcn_fence(__ATOMIC_ACQUIRE, "agent");
    }
    __syncthreads();
    hprev = hcur;
  }
}

// ---------------------------------------------------------------------------
// Output projection: out[b][s][o] = sum_h hs[s][h][b] * Who[o][h] + bho[o]
// ---------------------------------------------------------------------------
__global__ __launch_bounds__(256) void k_outproj(const float* __restrict__ hs,
                                                 const float* __restrict__ Who,
                                                 const float* __restrict__ bho,
                                                 float* __restrict__ out) {
  __shared__ float As[32][72];
  __shared__ float Bs[32][72];
  const int s  = blockIdx.y;
  const int o0 = blockIdx.x * 64;
  const int t  = threadIdx.x;
  const int tx = t & 15, ty = t >> 4;
  const float* __restrict__ hsS = hs + (size_t)s * HB;
  float acc[4][4] = {};
  for (int k0 = 0; k0 < H_; k0 += 32) {
    #pragma unroll
    for (int L = 0; L < 2; L++) {
      int f = L * 256 + t;
      int kk = f >> 4, b4 = (f & 15) * 4;
      *(float4*)&As[kk][b4] = *(const float4*)&hsS[(size_t)(k0 + kk) * 64 + b4];
    }
    #pragma unroll
    for (int L = 0; L < 2; L++) {
      int f = L * 256 + t;
      int row = f >> 3, c4 = (f & 7) * 4;   // row = o
      float4 v = *(const float4*)&Who[(size_t)(o0 + row) * H_ + k0 + c4];
      Bs[c4 + 0][row] = v.x;
      Bs[c4 + 1][row] = v.y;
      Bs[c4 + 2][row] = v.z;
      Bs[c4 + 3][row] = v.w;
    }
    __syncthreads();
    #pragma unroll
    for (int k = 0; k < 32; k += 4) {
      float4 a4[4], b4[4];
      #pragma unroll
      for (int kk = 0; kk < 4; kk++) a4[kk] = *(const float4*)&As[k + kk][ty * 4];
      #pragma unroll
      for (int kk = 0; kk < 4; kk++) b4[kk] = *(const float4*)&Bs[k + kk][tx * 4];
      #pragma unroll
      for (int kk = 0; kk < 4; kk++)
        #pragma unroll
        for (int r = 0; r < 4; r++)
          #pragma unroll
          for (int c = 0; c < 4; c++)
            acc[r][c] += ((const float*)&a4[kk])[r] * ((const float*)&b4[kk])[c];
    }
    __syncthreads();
  }
  #pragma unroll
  for (int r = 0; r < 4; r++) {
    int b = ty * 4 + r;
    float4 o4;
    o4.x = acc[r][0] + bho[o0 + tx * 4 + 0];
    o4.y = acc[r][1] + bho[o0 + tx * 4 + 1];
    o4.z = acc[r][2] + bho[o0 + tx * 4 + 2];
    o4.w = acc[r][3] + bho[o0 + tx * 4 + 3];
    *(float4*)&out[(size_t)b * (S_ * O_) + (size_t)s * O_ + o0 + tx * 4] = o4;
  }
}

// (B,H) -> (H,B)
__global__ void k_transpose_bh_to_hb(const float* __restrict__ src, float* __restrict__ dst) {
  int idx = blockIdx.x * 256 + threadIdx.x;  // 65536 total
  int h = idx >> 6, b = idx & 63;
  dst[h * 64 + b] = src[b * H_ + h];
}

// last hidden: (H,B) slice -> out (B,H)
__global__ void k_lasth(const float* __restrict__ hlast, float* __restrict__ out) {
  int idx = blockIdx.x * 256 + threadIdx.x;  // 65536 total
  int b = idx >> 10, h = idx & 1023;
  out[idx] = hlast[h * 64 + b];
}

extern "C" void kernel_launch(void* const* d_in, const int* in_sizes, int n_in,
                              void* d_out, int out_size, void* d_ws, size_t ws_size,
                              hipStream_t stream) {
  const float* x    = (const float*)d_in[0];
  const float* h0   = (const float*)d_in[1];
  const float* Wih  = (const float*)d_in[2];
  const float* bih  = (const float*)d_in[3];
  const float* Whh  = (const float*)d_in[4];
  const float* bhh  = (const float*)d_in[5];
  const float* Who  = (const float*)d_in[6];
  const float* bho  = (const float*)d_in[7];
  float* out = (float*)d_out;

  // ws: xp/hs (S,H,B) fp32 = 268.4 MB | hT0 (H,B) = 256 KB | 16 spread counters
  float*    xp  = (float*)d_ws;
  float*    hT0 = xp + (size_t)S_ * HB;
  unsigned* bar = (unsigned*)(hT0 + HB);

  hipMemsetAsync(bar, 0, NSLOT * SLOT_STRIDE * sizeof(unsigned), stream);
  k_transpose_bh_to_hb<<<256, 256, 0, stream>>>(h0, hT0);
  k_inproj<<<dim3(16, S_), 256, 0, stream>>>(x, Wih, bih, bhh, xp);

  void* args[] = {(void*)&hT0, (void*)&Whh, (void*)&xp, (void*)&bar};
  hipLaunchCooperativeKernel((const void*)k_scan, dim3(NBLK), dim3(NTHR),
                             args, 0, stream);

  k_outproj<<<dim3(8, S_), 256, 0, stream>>>(xp, Who, bho, out);
  k_lasth<<<256, 256, 0, stream>>>(xp + (size_t)(S_ - 1) * HB, out + (size_t)B_ * S_ * O_);
}

// Round 4
// 9645.058 us; speedup vs baseline: 2.6642x; 1.6974x over previous
//
#include <hip/hip_runtime.h>
#include <cmath>

#define B_ 64
#define S_ 1024
#define I_ 512
#define H_ 1024
#define O_ 512
#define HB (H_ * B_)   // 65536
#define SCAN_NBLK 64
#define SCAN_NTHR 512
#define NSLOT 16
#define SLOT_STRIDE 32   // 128 B between counters

typedef __attribute__((ext_vector_type(8))) __bf16 bf16x8;
typedef __attribute__((ext_vector_type(4))) float f32x4;

// frag layout for mfma_f32_16x16x32_bf16 B-operand: lane holds
// B[k = (lane>>4)*8 + j][n = lane&15]; tiles: kt = k>>5 (32 tiles), nt = b>>4 (4).
// ushort index of (k,b):
__device__ __forceinline__ int fragIdx(int k, int b) {
  int kt = k >> 5, q = (k >> 3) & 3, slot = k & 7;
  int nt = b >> 4, ln = q * 16 + (b & 15);
  return (((kt * 4 + nt) * 64) + ln) * 8 + slot;
}

// ---------------------------------------------------------------------------
// Input projection (unchanged): xp[s][h][b] = sum_i x[b][s][i]*Wih[h][i]+bih+bhh
// ---------------------------------------------------------------------------
__global__ __launch_bounds__(256) void k_inproj(const float* __restrict__ x,
                                                const float* __restrict__ Wih,
                                                const float* __restrict__ bih,
                                                const float* __restrict__ bhh,
                                                float* __restrict__ xp) {
  __shared__ float As[64][36];
  __shared__ float Bs[32][72];
  const int s  = blockIdx.y;
  const int h0 = blockIdx.x * 64;
  const int t  = threadIdx.x;
  const int tx = t & 15, ty = t >> 4;
  float acc[4][4] = {};
  for (int k0 = 0; k0 < I_; k0 += 32) {
    #pragma unroll
    for (int L = 0; L < 2; L++) {
      int f = L * 256 + t;
      int row = f >> 3, c4 = (f & 7) * 4;
      float4 v = *(const float4*)&Wih[(size_t)(h0 + row) * I_ + k0 + c4];
      *(float4*)&As[row][c4] = v;
    }
    #pragma unroll
    for (int L = 0; L < 2; L++) {
      int f = L * 256 + t;
      int row = f >> 3, c4 = (f & 7) * 4;   // row = b
      float4 v = *(const float4*)&x[(size_t)row * (S_ * I_) + (size_t)s * I_ + k0 + c4];
      Bs[c4 + 0][row] = v.x;
      Bs[c4 + 1][row] = v.y;
      Bs[c4 + 2][row] = v.z;
      Bs[c4 + 3][row] = v.w;
    }
    __syncthreads();
    #pragma unroll
    for (int k = 0; k < 32; k += 4) {
      float4 a[4], b[4];
      #pragma unroll
      for (int r = 0; r < 4; r++) a[r] = *(const float4*)&As[ty * 4 + r][k];
      #pragma unroll
      for (int kk = 0; kk < 4; kk++) b[kk] = *(const float4*)&Bs[k + kk][tx * 4];
      #pragma unroll
      for (int kk = 0; kk < 4; kk++)
        #pragma unroll
        for (int r = 0; r < 4; r++)
          #pragma unroll
          for (int c = 0; c < 4; c++)
            acc[r][c] += ((const float*)&a[r])[kk] * ((const float*)&b[kk])[c];
    }
    __syncthreads();
  }
  #pragma unroll
  for (int r = 0; r < 4; r++) {
    int h = h0 + ty * 4 + r;
    float bias = bih[h] + bhh[h];
    float4 o;
    o.x = acc[r][0] + bias;
    o.y = acc[r][1] + bias;
    o.z = acc[r][2] + bias;
    o.w = acc[r][3] + bias;
    *(float4*)&xp[(size_t)s * HB + (size_t)h * 64 + tx * 4] = o;
  }
}

// ---------------------------------------------------------------------------
// h0 (B,H) fp32 -> initial B-fragment arrays (hi/lo bf16 split)
// ---------------------------------------------------------------------------
__global__ void k_hfrag0(const float* __restrict__ h0,
                         unsigned short* __restrict__ hh,
                         unsigned short* __restrict__ hl) {
  int idx = blockIdx.x * 256 + threadIdx.x;  // 65536
  int b = idx >> 10, k = idx & 1023;
  float v = h0[(size_t)b * H_ + k];
  __bf16 h = (__bf16)v;
  __bf16 l = (__bf16)(v - (float)h);
  int fi = fragIdx(k, b);
  hh[fi] = __builtin_bit_cast(unsigned short, h);
  hl[fi] = __builtin_bit_cast(unsigned short, l);
}

// ---------------------------------------------------------------------------
// Persistent cooperative scan. 64 blocks x 512 threads. Block owns 16 j-rows.
// W_hh lives in VGPRs as bf16 hi/lo A-fragments (immune to buffer_inv).
// h handoff via pre-swizzled bf16 B-frag arrays (hi/lo, double-buffered),
// written sc1 (write-through to IF$), read as normal cached b128 loads after
// one acquire fence (buffer_inv) per block per step.
// ---------------------------------------------------------------------------
__global__ __launch_bounds__(SCAN_NTHR) void k_scan(
    const float* __restrict__ Whh, float* __restrict__ xp,
    unsigned short* __restrict__ hh0, unsigned short* __restrict__ hl0,
    unsigned short* __restrict__ hh1, unsigned short* __restrict__ hl1,
    unsigned* __restrict__ bar) {
  __shared__ float red[8 * 4 * 64 * 4];   // 32 KB: [w][nt][lane][reg]
  const int t    = threadIdx.x;
  const int lane = t & 63;
  const int w    = t >> 6;          // wave 0..7: k-slice [w*128, w*128+128)
  const int j0   = blockIdx.x * 16;
  const int m    = lane & 15, q = lane >> 4;

  // ---- one-time: W A-fragments, fp32 -> bf16 hi+lo split ----
  // A[m = lane&15][k = q*8 + j] per 16x32 tile; 4 tiles (kta) per wave.
  bf16x8 Ahi[4], Alo[4];
  #pragma unroll
  for (int kta = 0; kta < 4; kta++) {
    const float* src = Whh + (size_t)(j0 + m) * H_ + (w * 128 + kta * 32 + q * 8);
    float4 v0 = *(const float4*)src;
    float4 v1 = *(const float4*)(src + 4);
    float vv[8] = {v0.x, v0.y, v0.z, v0.w, v1.x, v1.y, v1.z, v1.w};
    #pragma unroll
    for (int j = 0; j < 8; j++) {
      __bf16 h = (__bf16)vv[j];
      __bf16 l = (__bf16)(vv[j] - (float)h);
      Ahi[kta][j] = h;
      Alo[kta][j] = l;
    }
  }

  const unsigned short* rdh = hh0;
  const unsigned short* rdl = hl0;
  unsigned short* wrh = hh1;
  unsigned short* wrl = hl1;

  for (int s = 0; s < S_; s++) {
    // ---- B-frag loads + MFMA (48 MFMA, 32 b128 loads per wave) ----
    f32x4 acc0 = 0.f, acc1 = 0.f, acc2 = 0.f, acc3 = 0.f;
    #pragma unroll
    for (int kta = 0; kta < 4; kta++) {
      const int ktg = w * 4 + kta;
      const unsigned short* ph = rdh + ((size_t)(ktg * 4) * 64 + lane) * 8;
      const unsigned short* pl = rdl + ((size_t)(ktg * 4) * 64 + lane) * 8;
      bf16x8 bh0 = __builtin_bit_cast(bf16x8, *(const uint4*)(ph + 0 * 512));
      bf16x8 bh1 = __builtin_bit_cast(bf16x8, *(const uint4*)(ph + 1 * 512));
      bf16x8 bh2 = __builtin_bit_cast(bf16x8, *(const uint4*)(ph + 2 * 512));
      bf16x8 bh3 = __builtin_bit_cast(bf16x8, *(const uint4*)(ph + 3 * 512));
      bf16x8 bl0 = __builtin_bit_cast(bf16x8, *(const uint4*)(pl + 0 * 512));
      bf16x8 bl1 = __builtin_bit_cast(bf16x8, *(const uint4*)(pl + 1 * 512));
      bf16x8 bl2 = __builtin_bit_cast(bf16x8, *(const uint4*)(pl + 2 * 512));
      bf16x8 bl3 = __builtin_bit_cast(bf16x8, *(const uint4*)(pl + 3 * 512));
      acc0 = __builtin_amdgcn_mfma_f32_16x16x32_bf16(Ahi[kta], bh0, acc0, 0, 0, 0);
      acc1 = __builtin_amdgcn_mfma_f32_16x16x32_bf16(Ahi[kta], bh1, acc1, 0, 0, 0);
      acc2 = __builtin_amdgcn_mfma_f32_16x16x32_bf16(Ahi[kta], bh2, acc2, 0, 0, 0);
      acc3 = __builtin_amdgcn_mfma_f32_16x16x32_bf16(Ahi[kta], bh3, acc3, 0, 0, 0);
      acc0 = __builtin_amdgcn_mfma_f32_16x16x32_bf16(Alo[kta], bh0, acc0, 0, 0, 0);
      acc1 = __builtin_amdgcn_mfma_f32_16x16x32_bf16(Alo[kta], bh1, acc1, 0, 0, 0);
      acc2 = __builtin_amdgcn_mfma_f32_16x16x32_bf16(Alo[kta], bh2, acc2, 0, 0, 0);
      acc3 = __builtin_amdgcn_mfma_f32_16x16x32_bf16(Alo[kta], bh3, acc3, 0, 0, 0);
      acc0 = __builtin_amdgcn_mfma_f32_16x16x32_bf16(Ahi[kta], bl0, acc0, 0, 0, 0);
      acc1 = __builtin_amdgcn_mfma_f32_16x16x32_bf16(Ahi[kta], bl1, acc1, 0, 0, 0);
      acc2 = __builtin_amdgcn_mfma_f32_16x16x32_bf16(Ahi[kta], bl2, acc2, 0, 0, 0);
      acc3 = __builtin_amdgcn_mfma_f32_16x16x32_bf16(Ahi[kta], bl3, acc3, 0, 0, 0);
    }
    // ---- cross-wave reduce via LDS ----
    *(f32x4*)&red[(((w * 4 + 0) * 64) + lane) * 4] = acc0;
    *(f32x4*)&red[(((w * 4 + 1) * 64) + lane) * 4] = acc1;
    *(f32x4*)&red[(((w * 4 + 2) * 64) + lane) * 4] = acc2;
    *(f32x4*)&red[(((w * 4 + 3) * 64) + lane) * 4] = acc3;
    __syncthreads();
    float* hcur = xp + (size_t)s * HB;
    #pragma unroll
    for (int rep = 0; rep < 2; rep++) {
      const int o = t + rep * 512;          // 1024 outputs: o = j*64 + b
      const int j = o >> 6, b = o & 63;
      const int nt = b >> 4, lc = (j >> 2) * 16 + (b & 15), reg = j & 3;
      float sum = 0.f;
      #pragma unroll
      for (int ww = 0; ww < 8; ww++)
        sum += red[(((ww * 4 + nt) * 64) + lc) * 4 + reg];
      const int jo = j0 + j;
      const size_t xi = (size_t)jo * 64 + b;
      float v = tanhf(hcur[xi] + sum);
      // publish fp32 h (for outproj) and bf16 hi/lo frags (for next step), sc1
      __hip_atomic_store(&hcur[xi], v, __ATOMIC_RELAXED, __HIP_MEMORY_SCOPE_AGENT);
      __bf16 hh = (__bf16)v;
      __bf16 hl = (__bf16)(v - (float)hh);
      const int fi = fragIdx(jo, b);
      __hip_atomic_store(&wrh[fi], __builtin_bit_cast(unsigned short, hh),
                         __ATOMIC_RELAXED, __HIP_MEMORY_SCOPE_AGENT);
      __hip_atomic_store(&wrl[fi], __builtin_bit_cast(unsigned short, hl),
                         __ATOMIC_RELAXED, __HIP_MEMORY_SCOPE_AGENT);
    }
    // ---- grid barrier (relaxed; one acquire fence per step afterwards) ----
    __syncthreads();   // drains vmcnt -> all sc1 stores at IF$ before arrival
    if (t == 0) {
      __hip_atomic_fetch_add(&bar[(blockIdx.x & (NSLOT - 1)) * SLOT_STRIDE], 1u,
                             __ATOMIC_RELAXED, __HIP_MEMORY_SCOPE_AGENT);
      const unsigned need = (unsigned)(s + 1) * SCAN_NBLK;
      for (;;) {
        unsigned tot = 0;
        #pragma unroll
        for (int i = 0; i < NSLOT; i++)
          tot += __hip_atomic_load(&bar[i * SLOT_STRIDE],
                                   __ATOMIC_RELAXED, __HIP_MEMORY_SCOPE_AGENT);
        if (tot >= need) break;
        __builtin_amdgcn_s_sleep(1);
      }
    }
    __syncthreads();
    if (t < 64) __builtin_amdgcn_fence(__ATOMIC_ACQUIRE, "agent");  // one buffer_inv
    __syncthreads();
    // swap double buffers
    const unsigned short* th = rdh; rdh = wrh; wrh = (unsigned short*)th;
    const unsigned short* tl = rdl; rdl = wrl; wrl = (unsigned short*)tl;
  }
}

// ---------------------------------------------------------------------------
// Output projection (unchanged): out[b][s][o] = sum_h hs[s][h][b]*Who[o][h]+bho
// ---------------------------------------------------------------------------
__global__ __launch_bounds__(256) void k_outproj(const float* __restrict__ hs,
                                                 const float* __restrict__ Who,
                                                 const float* __restrict__ bho,
                                                 float* __restrict__ out) {
  __shared__ float As[32][72];
  __shared__ float Bs[32][72];
  const int s  = blockIdx.y;
  const int o0 = blockIdx.x * 64;
  const int t  = threadIdx.x;
  const int tx = t & 15, ty = t >> 4;
  const float* __restrict__ hsS = hs + (size_t)s * HB;
  float acc[4][4] = {};
  for (int k0 = 0; k0 < H_; k0 += 32) {
    #pragma unroll
    for (int L = 0; L < 2; L++) {
      int f = L * 256 + t;
      int kk = f >> 4, b4 = (f & 15) * 4;
      *(float4*)&As[kk][b4] = *(const float4*)&hsS[(size_t)(k0 + kk) * 64 + b4];
    }
    #pragma unroll
    for (int L = 0; L < 2; L++) {
      int f = L * 256 + t;
      int row = f >> 3, c4 = (f & 7) * 4;   // row = o
      float4 v = *(const float4*)&Who[(size_t)(o0 + row) * H_ + k0 + c4];
      Bs[c4 + 0][row] = v.x;
      Bs[c4 + 1][row] = v.y;
      Bs[c4 + 2][row] = v.z;
      Bs[c4 + 3][row] = v.w;
    }
    __syncthreads();
    #pragma unroll
    for (int k = 0; k < 32; k += 4) {
      float4 a4[4], b4[4];
      #pragma unroll
      for (int kk = 0; kk < 4; kk++) a4[kk] = *(const float4*)&As[k + kk][ty * 4];
      #pragma unroll
      for (int kk = 0; kk < 4; kk++) b4[kk] = *(const float4*)&Bs[k + kk][tx * 4];
      #pragma unroll
      for (int kk = 0; kk < 4; kk++)
        #pragma unroll
        for (int r = 0; r < 4; r++)
          #pragma unroll
          for (int c = 0; c < 4; c++)
            acc[r][c] += ((const float*)&a4[kk])[r] * ((const float*)&b4[kk])[c];
    }
    __syncthreads();
  }
  #pragma unroll
  for (int r = 0; r < 4; r++) {
    int b = ty * 4 + r;
    float4 o4;
    o4.x = acc[r][0] + bho[o0 + tx * 4 + 0];
    o4.y = acc[r][1] + bho[o0 + tx * 4 + 1];
    o4.z = acc[r][2] + bho[o0 + tx * 4 + 2];
    o4.w = acc[r][3] + bho[o0 + tx * 4 + 3];
    *(float4*)&out[(size_t)b * (S_ * O_) + (size_t)s * O_ + o0 + tx * 4] = o4;
  }
}

// last hidden: (H,B) slice -> out (B,H)
__global__ void k_lasth(const float* __restrict__ hlast, float* __restrict__ out) {
  int idx = blockIdx.x * 256 + threadIdx.x;  // 65536 total
  int b = idx >> 10, h = idx & 1023;
  out[idx] = hlast[h * 64 + b];
}

extern "C" void kernel_launch(void* const* d_in, const int* in_sizes, int n_in,
                              void* d_out, int out_size, void* d_ws, size_t ws_size,
                              hipStream_t stream) {
  const float* x    = (const float*)d_in[0];
  const float* h0   = (const float*)d_in[1];
  const float* Wih  = (const float*)d_in[2];
  const float* bih  = (const float*)d_in[3];
  const float* Whh  = (const float*)d_in[4];
  const float* bhh  = (const float*)d_in[5];
  const float* Who  = (const float*)d_in[6];
  const float* bho  = (const float*)d_in[7];
  float* out = (float*)d_out;

  // ws: xp/hs (S,H,B) fp32 = 268.4 MB | 4 frag arrays 128 KB each | counters
  float* xp = (float*)d_ws;
  unsigned short* hh0 = (unsigned short*)(xp + (size_t)S_ * HB);
  unsigned short* hl0 = hh0 + HB;
  unsigned short* hh1 = hl0 + HB;
  unsigned short* hl1 = hh1 + HB;
  unsigned* bar = (unsigned*)(hl1 + HB);

  hipMemsetAsync(bar, 0, NSLOT * SLOT_STRIDE * sizeof(unsigned), stream);
  k_hfrag0<<<256, 256, 0, stream>>>(h0, hh0, hl0);
  k_inproj<<<dim3(16, S_), 256, 0, stream>>>(x, Wih, bih, bhh, xp);

  void* args[] = {(void*)&Whh, (void*)&xp, (void*)&hh0, (void*)&hl0,
                  (void*)&hh1, (void*)&hl1, (void*)&bar};
  hipLaunchCooperativeKernel((const void*)k_scan, dim3(SCAN_NBLK), dim3(SCAN_NTHR),
                             args, 0, stream);

  k_outproj<<<dim3(8, S_), 256, 0, stream>>>(xp, Who, bho, out);
  k_lasth<<<256, 256, 0, stream>>>(xp + (size_t)(S_ - 1) * HB, out + (size_t)B_ * S_ * O_);
}